// Round 1
// baseline (276.972 us; speedup 1.0000x reference)
//
#include <hip/hip_runtime.h>

#define B_ 4
#define L_ 4096
#define D_ 1152
#define T_ (B_*L_)      // 16384 tokens
#define D3_ 384
#define H_ 16
#define DK3_ 24

typedef __attribute__((ext_vector_type(4))) float f32x4;
typedef __attribute__((ext_vector_type(8))) __bf16 bf16x8;
typedef __attribute__((ext_vector_type(8))) unsigned short u16x8;

__device__ __forceinline__ unsigned short f2bf(float f) {
  unsigned int u = __float_as_uint(f);
  u += 0x7fffu + ((u >> 16) & 1u);   // round-to-nearest-even
  return (unsigned short)(u >> 16);
}
__device__ __forceinline__ float bf2f(unsigned short h) {
  return __uint_as_float(((unsigned int)h) << 16);
}

// ---------------- LayerNorm: fp32 [16384,1152] -> bf16 [16384,1152] ----------------
__global__ __launch_bounds__(256) void ln_kernel(const float* __restrict__ x,
                                                 const float* __restrict__ gamma,
                                                 const float* __restrict__ beta,
                                                 unsigned short* __restrict__ xn) {
  const int row = blockIdx.x;
  const int tid = threadIdx.x;
  const float* xr = x + (size_t)row * D_;
  float v[5];
  float s = 0.f, s2 = 0.f;
#pragma unroll
  for (int j = 0; j < 5; ++j) {
    int idx = tid + j * 256;
    float val = (idx < D_) ? xr[idx] : 0.f;
    v[j] = val;
    s += val; s2 += val * val;
  }
#pragma unroll
  for (int o = 32; o > 0; o >>= 1) { s += __shfl_down(s, o); s2 += __shfl_down(s2, o); }
  __shared__ float red[8];
  int wid = tid >> 6, lane = tid & 63;
  if (lane == 0) { red[wid] = s; red[4 + wid] = s2; }
  __syncthreads();
  float ts  = red[0] + red[1] + red[2] + red[3];
  float ts2 = red[4] + red[5] + red[6] + red[7];
  const float inv = 1.f / (float)D_;
  float mean = ts * inv;
  float var  = ts2 * inv - mean * mean;
  float rstd = rsqrtf(var + 1e-6f);
  unsigned short* xo = xn + (size_t)row * D_;
#pragma unroll
  for (int j = 0; j < 5; ++j) {
    int idx = tid + j * 256;
    if (idx < D_) {
      float nv = (v[j] - mean) * rstd * gamma[idx] + beta[idx];
      xo[idx] = f2bf(nv);
    }
  }
}

// ---------------- Weight converts ----------------
__global__ void cvt_cat_wqkvg(const float* __restrict__ Wq, const float* __restrict__ Wk,
                              const float* __restrict__ Wv, const float* __restrict__ Wg,
                              unsigned short* __restrict__ out) {
  int i = blockIdx.x * 256 + threadIdx.x;
  if (i >= 4 * 147456) return;
  int p = i / 147456;
  int r = i - p * 147456;
  const float* W = (p == 0) ? Wq : (p == 1) ? Wk : (p == 2) ? Wv : Wg;
  out[i] = f2bf(W[r]);
}

__global__ void cvt_bf16(const float* __restrict__ in, unsigned short* __restrict__ out, int n) {
  int i = blockIdx.x * 256 + threadIdx.x;
  if (i < n) out[i] = f2bf(in[i]);
}

// ---------------- bf16 GEMM: C[M,N] = A[M,K] @ Bt[N,K]^T (+epilogue) ----------------
// 128x128 tile, BK=32, 4 waves (2x2), 4x4 16x16x32 fragments per wave.
// Reg-staged global->LDS, padded LDS stride 40 (2-way bank aliasing only).
#define LDSW 40

template<int EPI>
__global__ __launch_bounds__(256) void gemm_bt(
    const unsigned short* __restrict__ A, const unsigned short* __restrict__ Bt,
    int K, int N,
    unsigned short* __restrict__ Cb,
    const float* __restrict__ b0, const float* __restrict__ b1,
    const float* __restrict__ b2, const float* __restrict__ b3,
    float* __restrict__ Cf, const float* __restrict__ bo,
    const float* __restrict__ xres, const float* __restrict__ gs) {
  __shared__ __align__(16) unsigned short As[128 * LDSW];
  __shared__ __align__(16) unsigned short Bs[128 * LDSW];
  const int tid = threadIdx.x;
  const int bm = blockIdx.y, bn = blockIdx.x;
  const int wid = tid >> 6, lane = tid & 63;
  const int wr = wid >> 1, wc = wid & 1;
  const int lrow = lane & 15, kq = lane >> 4;

  const int sr0 = tid >> 2,        sc0 = (tid & 3) * 8;
  const int sr1 = (tid + 256) >> 2, sc1 = sc0;   // li1 = tid+256: same (li&3)

  const unsigned short* Ab = A + (size_t)bm * 128 * K;
  const unsigned short* Bb = Bt + (size_t)bn * 128 * K;

  u16x8 ra0 = *(const u16x8*)(Ab + (size_t)sr0 * K + sc0);
  u16x8 ra1 = *(const u16x8*)(Ab + (size_t)sr1 * K + sc1);
  u16x8 rb0 = *(const u16x8*)(Bb + (size_t)sr0 * K + sc0);
  u16x8 rb1 = *(const u16x8*)(Bb + (size_t)sr1 * K + sc1);

  f32x4 acc[4][4];
#pragma unroll
  for (int m = 0; m < 4; ++m)
#pragma unroll
    for (int n = 0; n < 4; ++n) acc[m][n] = (f32x4){0.f, 0.f, 0.f, 0.f};

  const int nk = K >> 5;
  for (int kt = 0; kt < nk; ++kt) {
    __syncthreads();
    *(u16x8*)&As[sr0 * LDSW + sc0] = ra0;
    *(u16x8*)&As[sr1 * LDSW + sc1] = ra1;
    *(u16x8*)&Bs[sr0 * LDSW + sc0] = rb0;
    *(u16x8*)&Bs[sr1 * LDSW + sc1] = rb1;
    __syncthreads();
    if (kt + 1 < nk) {
      const unsigned short* An = Ab + (kt + 1) * 32;
      const unsigned short* Bn = Bb + (kt + 1) * 32;
      ra0 = *(const u16x8*)(An + (size_t)sr0 * K + sc0);
      ra1 = *(const u16x8*)(An + (size_t)sr1 * K + sc1);
      rb0 = *(const u16x8*)(Bn + (size_t)sr0 * K + sc0);
      rb1 = *(const u16x8*)(Bn + (size_t)sr1 * K + sc1);
    }
    bf16x8 af[4], bfr[4];
#pragma unroll
    for (int m = 0; m < 4; ++m)
      af[m] = *(const bf16x8*)&As[(wr * 64 + m * 16 + lrow) * LDSW + kq * 8];
#pragma unroll
    for (int n = 0; n < 4; ++n)
      bfr[n] = *(const bf16x8*)&Bs[(wc * 64 + n * 16 + lrow) * LDSW + kq * 8];
#pragma unroll
    for (int m = 0; m < 4; ++m)
#pragma unroll
      for (int n = 0; n < 4; ++n)
        acc[m][n] = __builtin_amdgcn_mfma_f32_16x16x32_bf16(af[m], bfr[n], acc[m][n], 0, 0, 0);
  }

  // Epilogue. D layout: col = lane&15, row = (lane>>4)*4 + reg  [m89-verified]
  const int rbase = bm * 128 + wr * 64 + kq * 4;
  const int cbase = bn * 128 + wc * 64 + lrow;
  float gv = (EPI == 1) ? gs[0] : 0.f;
#pragma unroll
  for (int m = 0; m < 4; ++m) {
#pragma unroll
    for (int n = 0; n < 4; ++n) {
      int col = cbase + n * 16;
      float bias;
      if (EPI == 0) {
        int p = (col < 384) ? 0 : (col < 768) ? 1 : (col < 1152) ? 2 : 3;
        const float* bp = (p == 0) ? b0 : (p == 1) ? b1 : (p == 2) ? b2 : b3;
        bias = bp[col - p * 384];
      } else {
        bias = bo[col];
      }
#pragma unroll
      for (int i = 0; i < 4; ++i) {
        int row = rbase + m * 16 + i;
        float val = acc[m][n][i] + bias;
        if (EPI == 0) {
          Cb[(size_t)row * N + col] = f2bf(val);
        } else {
          size_t idx = (size_t)row * N + col;
          Cf[idx] = val + xres[idx] * gv;
        }
      }
    }
  }
}

// ---------------- 3x3 attention + gate: QKVG bf16 [49152,1536] -> H bf16 [16384,1152] ----------------
__global__ __launch_bounds__(256) void attn_kernel(const unsigned short* __restrict__ QKVG,
                                                   unsigned short* __restrict__ Hout) {
  int u = blockIdx.x * 256 + threadIdx.x;   // u = t*48 + i*16 + h
  int h = u & 15;
  int ti = u >> 4;                          // = t*3 + i
  int i = ti % 3;
  int t = ti / 3;
  const unsigned short* base = QKVG + (size_t)t * 3 * 1536;
  const int co = h * 24;

  float q[24];
#pragma unroll
  for (int c = 0; c < 3; ++c) {
    u16x8 w = *(const u16x8*)(base + (size_t)i * 1536 + co + c * 8);
#pragma unroll
    for (int e = 0; e < 8; ++e) q[c * 8 + e] = bf2f(w[e]);
  }
  float s[3];
#pragma unroll
  for (int j = 0; j < 3; ++j) {
    float a = 0.f;
#pragma unroll
    for (int c = 0; c < 3; ++c) {
      u16x8 w = *(const u16x8*)(base + (size_t)j * 1536 + 384 + co + c * 8);
#pragma unroll
      for (int e = 0; e < 8; ++e) a += q[c * 8 + e] * bf2f(w[e]);
    }
    s[j] = a * 0.11785113019775793f;  // 1/sqrt(72)
  }
  float mx = fmaxf(s[0], fmaxf(s[1], s[2]));
  float e0 = __expf(s[0] - mx), e1 = __expf(s[1] - mx), e2 = __expf(s[2] - mx);
  float inv = 1.f / (e0 + e1 + e2);
  float p0 = e0 * inv, p1 = e1 * inv, p2 = e2 * inv;

  float o[24];
#pragma unroll
  for (int d = 0; d < 24; ++d) o[d] = 0.f;
  float pj[3] = {p0, p1, p2};
#pragma unroll
  for (int j = 0; j < 3; ++j) {
#pragma unroll
    for (int c = 0; c < 3; ++c) {
      u16x8 w = *(const u16x8*)(base + (size_t)j * 1536 + 768 + co + c * 8);
#pragma unroll
      for (int e = 0; e < 8; ++e) o[c * 8 + e] += pj[j] * bf2f(w[e]);
    }
  }
  unsigned short* op = Hout + (size_t)t * 1152 + (size_t)i * 384 + co;
#pragma unroll
  for (int c = 0; c < 3; ++c) {
    u16x8 w = *(const u16x8*)(base + (size_t)i * 1536 + 1152 + co + c * 8);
    u16x8 r;
#pragma unroll
    for (int e = 0; e < 8; ++e) {
      float gv = bf2f(w[e]);
      float sg = 1.f / (1.f + __expf(-gv));
      r[e] = f2bf(o[c * 8 + e] * sg);
    }
    *(u16x8*)(op + c * 8) = r;
  }
}

extern "C" void kernel_launch(void* const* d_in, const int* in_sizes, int n_in,
                              void* d_out, int out_size, void* d_ws, size_t ws_size,
                              hipStream_t stream) {
  const float* x    = (const float*)d_in[0];
  const float* ln_g = (const float*)d_in[1];
  const float* ln_b = (const float*)d_in[2];
  const float* Wq   = (const float*)d_in[3];
  const float* bq   = (const float*)d_in[4];
  const float* Wk   = (const float*)d_in[5];
  const float* bk   = (const float*)d_in[6];
  const float* Wv   = (const float*)d_in[7];
  const float* bv   = (const float*)d_in[8];
  const float* Wg   = (const float*)d_in[9];
  const float* bg   = (const float*)d_in[10];
  const float* Wo   = (const float*)d_in[11];
  const float* bo   = (const float*)d_in[12];
  const float* g    = (const float*)d_in[13];
  float* out = (float*)d_out;

  char* ws = (char*)d_ws;
  size_t off = 0;
  unsigned short* xn    = (unsigned short*)(ws + off); off += (size_t)T_ * D_ * 2;        // 37,748,736
  unsigned short* Wqkvg = (unsigned short*)(ws + off); off += (size_t)1536 * 384 * 2;     //  1,179,648
  unsigned short* Wob   = (unsigned short*)(ws + off); off += (size_t)1152 * 1152 * 2;    //  2,654,208
  unsigned short* QKVG  = (unsigned short*)(ws + off); off += (size_t)T_ * 3 * 1536 * 2;  // 150,994,944
  unsigned short* Hf    = (unsigned short*)(ws + off); off += (size_t)T_ * D_ * 2;        // 37,748,736
  // total ~230 MB

  ln_kernel<<<T_, 256, 0, stream>>>(x, ln_g, ln_b, xn);
  cvt_cat_wqkvg<<<(4 * 147456 + 255) / 256, 256, 0, stream>>>(Wq, Wk, Wv, Wg, Wqkvg);
  cvt_bf16<<<(1152 * 1152 + 255) / 256, 256, 0, stream>>>(Wo, Wob, 1152 * 1152);

  dim3 g1(1536 / 128, (T_ * 3) / 128);   // (12, 384)
  gemm_bt<0><<<g1, 256, 0, stream>>>(xn, Wqkvg, 384, 1536, QKVG, bq, bk, bv, bg,
                                     nullptr, nullptr, nullptr, nullptr);

  attn_kernel<<<(T_ * H_ * 3) / 256, 256, 0, stream>>>(QKVG, Hf);

  dim3 g2(1152 / 128, T_ / 128);         // (9, 128)
  gemm_bt<1><<<g2, 256, 0, stream>>>(Hf, Wob, 1152, 1152,
                                     nullptr, nullptr, nullptr, nullptr, nullptr,
                                     out, bo, x, g);
}